// Round 20
// baseline (396.444 us; speedup 1.0000x reference)
//
#include <hip/hip_runtime.h>
#include <hip/hip_fp16.h>

// clusteringEMA: B=65536, D=512, K=1024, C=100
// R20: 3-blocks/CU argmin (the TLP lever: 1blk=260us, 2blk=141us measured).
// 64-row blocks (grid 1024), wave tile 32x128, acc[2][8]; A dbuf 2x8KB
// (same XOR maps, 16 rows/wave), B dbuf 2x16KB (r17 k-paired, byte-identical
// maps), wsq from global. LDS 50688B -> 3 blocks/CU. Tail = r19 verbatim.

#define NB 65536
#define ND 512
#define NK 1024
#define NC 100
#define TAU 0.25f
#define FLAG_CAP 16384
#define FROWS 8
#define GROWS 128

typedef unsigned int u32;
typedef unsigned short u16;
typedef unsigned long long u64;
typedef __attribute__((ext_vector_type(8))) _Float16 half8v;
typedef __attribute__((ext_vector_type(4))) float f32x4;

// ---------------- ws layout (4-byte units) ----------------
#define OFF_COUNTS   0          // int [1024]
#define OFF_CURSOR   1024       // int [1024]
#define OFF_BHIST    2048       // float [102400]
#define OFF_FLAGCNT  104448     // int [64]
#define OFF_WSQ      104512     // float [1024]
#define OFF_ZERO_END 105536
#define OFF_FLAGLIST 105536     // int [16384]
#define OFF_ARGMIN   156736     // int [65536]
#define OFF_ORDER    222272     // int [65536]
#define OFF_KORDER   287808     // int [65536]
#define OFF_WTHI     353344     // u16 [524288] = 262144 float slots
#define OFF_WT32     615488     // float [524288]
#define OFF_XH       1139776    // u16 [33554432] = 16777216 float slots
#define OFF_ESUM     17916992   // float [524288]

__device__ inline f32x4 mfma16f(half8v a, half8v b, f32x4 c) {
  return __builtin_amdgcn_mfma_f32_16x16x32_f16(a, b, c, 0, 0, 0);
}

__device__ __forceinline__ void gl_lds16(const u16* g, u16* l) {
  __builtin_amdgcn_global_load_lds(
      (const __attribute__((address_space(1))) u32*)g,
      (__attribute__((address_space(3))) u32*)l, 16, 0, 0);
}

__device__ inline u32 f32_sortable(float f) {
  u32 b = __float_as_uint(f);
  return (b & 0x80000000u) ? ~b : (b | 0x80000000u);
}

__device__ inline half8v cvt8_f16(const float4& a, const float4& b) {
  half8v h;
  h[0] = (_Float16)a.x; h[1] = (_Float16)a.y;
  h[2] = (_Float16)a.z; h[3] = (_Float16)a.w;
  h[4] = (_Float16)b.x; h[5] = (_Float16)b.y;
  h[6] = (_Float16)b.z; h[7] = (_Float16)b.w;
  return h;
}

// ------ kernel 1: fused prep: blocks [0,512) = W transpose+split+wsq;
//                  blocks [512, 512+16384) = X -> Xh f16 ------
__global__ __launch_bounds__(256) void prep_all(const float* __restrict__ W,
                                                const float* __restrict__ X,
                                                u16* __restrict__ Wthi,
                                                float* __restrict__ Wt32,
                                                u16* __restrict__ Xh,
                                                float* __restrict__ wsq) {
  __shared__ float tile[32][33];
  int t = threadIdx.x;
  if (blockIdx.x >= 512) {
    size_t i = ((size_t)(blockIdx.x - 512) * 256 + t) * 8;
    float4 a = *(const float4*)(X + i);
    float4 b = *(const float4*)(X + i + 4);
    *(half8v*)(Xh + i) = cvt8_f16(a, b);
    return;
  }
  int db = blockIdx.x & 15;
  int kb = blockIdx.x >> 4;
  int tx = t & 31, ty = t >> 5;
  float s = 0.f;
#pragma unroll
  for (int i = 0; i < 4; ++i) {
    int d = db * 32 + ty + 8 * i;
    float wv = W[(size_t)d * NK + kb * 32 + tx];
    tile[ty + 8 * i][tx] = wv;
    s += wv * wv;
  }
  atomicAdd(&wsq[kb * 32 + tx], s);
  __syncthreads();
#pragma unroll
  for (int i = 0; i < 4; ++i) {
    int kl = ty + 8 * i;
    float f = tile[tx][kl];
    size_t o = (size_t)(kb * 32 + kl) * ND + db * 32 + tx;
    Wt32[o] = f;
    Wthi[o] = __half_as_ushort(__float2half(f));
  }
}

// --- kernel 2: argmin MFMA, 64-row blocks, 3 blocks/CU ----------------------
__global__ __launch_bounds__(256, 3) void argmin_t64(
    const u16* __restrict__ Xh, const u16* __restrict__ Wthi,
    const float* __restrict__ wsq, const int* __restrict__ cls,
    int* __restrict__ argmin_i, float* __restrict__ argmin_f,
    int* __restrict__ counts, float* __restrict__ bhist,
    int* __restrict__ flagCnt, int* __restrict__ flagList) {
  __shared__ __align__(16) u16 Ah[2 * 64 * 64];    // 16 KB (BK=64 chunks)
  __shared__ __align__(16) u16 Bh[2 * 128 * 64];   // 32 KB (k-paired rows)
  __shared__ float redV[64][2];
  __shared__ float redS[64][2];
  __shared__ int redI[64][2];                      // total 50688 B

  const int t = threadIdx.x;
  const int lane = t & 63;
  const int w = t >> 6;
  const int g = lane >> 4;
  const int l15 = lane & 15;
  const int wrb = (w >> 1) * 32;    // wave row base (0/32)
  const int wcb = (w & 1) * 128;    // wave col base within the 256-col tile
  const int brow = blockIdx.x * 64;

  // A staging: wave w stages rows w*16 .. w*16+15 (2 issues of 8 rows);
  // lane -> row sub = lane>>3, phys chunk c8p = lane&7; src chunk = c8p^sub
  const int sub = lane >> 3;
  const int c8p = lane & 7;
  const size_t asrc = (size_t)(brow + w * 16 + sub) * ND + (size_t)((c8p ^ sub) * 8);

  // B staging, k-paired layout (r17, measured 0 conflicts; block-row indep)
  const size_t bsrc = (size_t)(2 * (w * 32 + sub) + (c8p >> 2)) * ND +
                      (size_t)(((c8p & 3) ^ (sub & 3)) * 8);

  // fragment read offsets (u16 units); m stride = 16 rows = 1024 u16
  int aofs[2];
#pragma unroll
  for (int kk = 0; kk < 2; ++kk)
    aofs[kk] = (wrb + l15) * 64 + (((kk * 4 + g) ^ (l15 & 7)) * 8);
  const int bofs = wcb * 32 + (l15 >> 1) * 64 + (l15 & 1) * 32 +
                   ((g ^ ((l15 >> 1) & 3)) * 8);

  float bestV[2][4], secV[2][4];
  int bestI[2][4];
#pragma unroll
  for (int m = 0; m < 2; ++m)
#pragma unroll
    for (int r = 0; r < 4; ++r) {
      bestV[m][r] = 3.4e38f; secV[m][r] = 3.4e38f; bestI[m][r] = 0;
    }

  f32x4 acc[2][8];
#pragma unroll
  for (int m = 0; m < 2; ++m)
#pragma unroll
    for (int n = 0; n < 8; ++n) acc[m][n] = (f32x4)0.f;

#define ISSUE_A(kc_, ab_)                                                \
  {                                                                      \
    const u16* as_ = Xh + asrc + (kc_) * 64;                             \
    u16* ad_ = Ah + (ab_) * 4096 + w * 16 * 64;                          \
    gl_lds16(as_, ad_);                                                  \
    gl_lds16(as_ + (size_t)8 * ND, ad_ + 8 * 64);                        \
  }
#define ISSUE_B(ct_, sk_, bb_)                                           \
  {                                                                      \
    const u16* bs_ = Wthi + (size_t)(ct_) * 256 * ND + bsrc + (sk_) * 32;\
    u16* bd_ = Bh + (bb_) * 8192 + w * 32 * 64;                          \
    _Pragma("unroll")                                                    \
    for (int q = 0; q < 4; ++q)                                          \
      gl_lds16(bs_ + (size_t)(q * 16) * ND, bd_ + q * 8 * 64);           \
  }
#define DRAIN asm volatile("s_waitcnt vmcnt(0) lgkmcnt(0)" ::: "memory")

  ISSUE_A(0, 0);
  ISSUE_B(0, 0, 0);
  DRAIN;
  __syncthreads();

  for (int s = 0; s < 64; ++s) {
    const int sk = s & 15;
    const int kpar = s & 1;
    const int abuf = (s >> 1) & 1;
    const int bbuf = s & 1;
    if (s < 63) {
      const int s1 = s + 1;
      ISSUE_B(s1 >> 4, s1 & 15, s1 & 1);
      if (s & 1) ISSUE_A(((s1 & 15) >> 1), (s1 >> 1) & 1);
    }
    const u16* Ab = Ah + abuf * 4096;
    const u16* Bb = Bh + bbuf * 8192;
    {
      half8v a_h[2];
#pragma unroll
      for (int m = 0; m < 2; ++m)
        a_h[m] = *(const half8v*)&Ab[aofs[kpar] + m * 1024];
#pragma unroll
      for (int n = 0; n < 8; ++n) {
        half8v b_h = *(const half8v*)&Bb[bofs + n * 512];
#pragma unroll
        for (int m = 0; m < 2; ++m)
          acc[m][n] = mfma16f(a_h[m], b_h, acc[m][n]);
      }
    }
    if (sk == 15) {
      const int ct = s >> 4;
      // epilogue for ct. C layout: col = 16n + l15, row = 16m + 4g + r
#pragma unroll
      for (int n = 0; n < 8; ++n) {
        int col = ct * 256 + wcb + 16 * n + l15;
        float wq = wsq[col];   // global, L2-resident
#pragma unroll
        for (int m = 0; m < 2; ++m)
#pragma unroll
          for (int r = 0; r < 4; ++r) {
            float v = wq - 2.0f * acc[m][n][r];
            if (v < bestV[m][r]) {
              secV[m][r] = bestV[m][r];
              bestV[m][r] = v;
              bestI[m][r] = col;
            } else if (v < secV[m][r]) {
              secV[m][r] = v;
            }
          }
      }
#pragma unroll
      for (int m = 0; m < 2; ++m)
#pragma unroll
        for (int n = 0; n < 8; ++n) acc[m][n] = (f32x4)0.f;
    }
    DRAIN;
    __syncthreads();
  }
#undef ISSUE_A
#undef ISSUE_B
#undef DRAIN

  // cross-lane reduce: 16 lanes share each row; merge (b1,idx,b2)
#pragma unroll
  for (int m = 0; m < 2; ++m)
#pragma unroll
    for (int r = 0; r < 4; ++r) {
      float v = bestV[m][r];
      float sec = secV[m][r];
      int idx = bestI[m][r];
#pragma unroll
      for (int mask = 1; mask < 16; mask <<= 1) {
        float ov = __shfl_xor(v, mask, 64);
        float os = __shfl_xor(sec, mask, 64);
        int oi = __shfl_xor(idx, mask, 64);
        float nsec = fminf(fminf(sec, os), fmaxf(v, ov));
        if (ov < v || (ov == v && oi < idx)) { v = ov; idx = oi; }
        sec = nsec;
      }
      if (l15 == 0) {
        int rowl = wrb + 16 * m + 4 * g + r;
        redV[rowl][w & 1] = v;
        redS[rowl][w & 1] = sec;
        redI[rowl][w & 1] = idx;
      }
    }
  __syncthreads();
  if (t < 64) {
    float v0 = redV[t][0], v1 = redV[t][1];
    float s0 = redS[t][0], s1 = redS[t][1];
    int i0 = redI[t][0], i1 = redI[t][1];
    float bv, sec;
    int bi;
    if (v1 < v0 || (v1 == v0 && i1 < i0)) { bv = v1; bi = i1; }
    else { bv = v0; bi = i0; }
    sec = fminf(fminf(s0, s1), fmaxf(v0, v1));
    int b = brow + t;
    argmin_i[b] = bi;
    argmin_f[b] = (float)bi;
    atomicAdd(&counts[bi], 1);
    atomicAdd(&bhist[(size_t)bi * NC + cls[b]], 1.0f);
    if (sec - bv < TAU) {
      int slot = atomicAdd(flagCnt, 1);
      if (slot < FLAG_CAP) flagList[slot] = b;
    }
  }
}

// ----- kernel 3: exact f32 rescore + in-place apply (block owns its rows) ---
__global__ __launch_bounds__(256) void fixup_kernel(
    const float* __restrict__ X, const float* __restrict__ Wt32,
    const float* __restrict__ wsq, const int* __restrict__ flagCnt,
    const int* __restrict__ flagList, const int* __restrict__ cls,
    int* __restrict__ argmin_i, float* __restrict__ argmin_f,
    int* __restrict__ counts, float* __restrict__ bhist) {
  __shared__ float xs[FROWS][ND];
  __shared__ int rows[FROWS];
  __shared__ u64 wred[4][FROWS];
  int n = *flagCnt;
  if (n > FLAG_CAP) n = FLAG_CAP;
  int r0 = blockIdx.x * FROWS;
  if (r0 >= n) return;
  int nr = n - r0; if (nr > FROWS) nr = FROWS;
  int t = threadIdx.x;
  if (t < FROWS) rows[t] = flagList[r0 + (t < nr ? t : 0)];
  __syncthreads();
  for (int j = t; j < FROWS * (ND / 4); j += 256) {
    int r = j >> 7, c = j & 127;
    ((float4*)xs[r])[c] = ((const float4*)(X + (size_t)rows[r] * ND))[c];
  }
  __syncthreads();

  const int k0 = t * 4;
  const float4* w0 = (const float4*)(Wt32 + (size_t)(k0 + 0) * ND);
  const float4* w1 = (const float4*)(Wt32 + (size_t)(k0 + 1) * ND);
  const float4* w2 = (const float4*)(Wt32 + (size_t)(k0 + 2) * ND);
  const float4* w3 = (const float4*)(Wt32 + (size_t)(k0 + 3) * ND);
  float a[4][FROWS];
#pragma unroll
  for (int kk = 0; kk < 4; ++kk)
#pragma unroll
    for (int r = 0; r < FROWS; ++r) a[kk][r] = 0.f;

  for (int d = 0; d < ND / 4; ++d) {
    float4 v0 = w0[d], v1 = w1[d], v2 = w2[d], v3 = w3[d];
#pragma unroll
    for (int r = 0; r < FROWS; ++r) {
      float4 x4 = ((const float4*)xs[r])[d];
      a[0][r] += x4.x * v0.x + x4.y * v0.y + x4.z * v0.z + x4.w * v0.w;
      a[1][r] += x4.x * v1.x + x4.y * v1.y + x4.z * v1.z + x4.w * v1.w;
      a[2][r] += x4.x * v2.x + x4.y * v2.y + x4.z * v2.z + x4.w * v2.w;
      a[3][r] += x4.x * v3.x + x4.y * v3.y + x4.z * v3.z + x4.w * v3.w;
    }
  }

  float wq0 = wsq[k0], wq1 = wsq[k0 + 1], wq2 = wsq[k0 + 2], wq3 = wsq[k0 + 3];
  const int wv_ = t >> 6, lane = t & 63;
#pragma unroll
  for (int r = 0; r < FROWS; ++r) {
    float bv = wq0 - 2.0f * a[0][r];
    int bk = k0;
    float v;
    v = wq1 - 2.0f * a[1][r]; if (v < bv) { bv = v; bk = k0 + 1; }
    v = wq2 - 2.0f * a[2][r]; if (v < bv) { bv = v; bk = k0 + 2; }
    v = wq3 - 2.0f * a[3][r]; if (v < bv) { bv = v; bk = k0 + 3; }
    u64 key = ((u64)f32_sortable(bv) << 32) | (u32)bk;
#pragma unroll
    for (int m = 1; m < 64; m <<= 1) {
      u64 o = __shfl_xor(key, m, 64);
      if (o < key) key = o;
    }
    if (lane == 0) wred[wv_][r] = key;
  }
  __syncthreads();
  if (t < nr) {
    u64 k = wred[0][t];
    if (wred[1][t] < k) k = wred[1][t];
    if (wred[2][t] < k) k = wred[2][t];
    if (wred[3][t] < k) k = wred[3][t];
    int nk = (int)(u32)(k & 0xffffffffu);
    int row = rows[t];
    int old = argmin_i[row];
    if (nk != old) {
      argmin_i[row] = nk;
      argmin_f[row] = (float)nk;
      atomicSub(&counts[old], 1);
      atomicAdd(&counts[nk], 1);
      int c = cls[row];
      atomicAdd(&bhist[(size_t)old * NC + c], -1.0f);
      atomicAdd(&bhist[(size_t)nk * NC + c], 1.0f);
    }
  }
}

// --------- kernel 4: reorder rows + in-block offsets scan + zero esum -------
__global__ __launch_bounds__(256) void reorder_kernel(
    const int* __restrict__ argmin_i, const int* __restrict__ counts,
    int* __restrict__ cursor, int* __restrict__ order,
    int* __restrict__ korder, float* __restrict__ esum) {
  __shared__ int offs[NK];
  __shared__ int wpart[4];
  int t = threadIdx.x, lane = t & 63, wv = t >> 6;
  int b = blockIdx.x * 256 + t;

  float4 z = make_float4(0.f, 0.f, 0.f, 0.f);
  *(float4*)(esum + (size_t)b * 8) = z;
  *(float4*)(esum + (size_t)b * 8 + 4) = z;

  int4 c4 = ((const int4*)counts)[t];
  int lsum = c4.x + c4.y + c4.z + c4.w;
  int ic = lsum;
#pragma unroll
  for (int o = 1; o < 64; o <<= 1) {
    int v = __shfl_up(ic, o, 64);
    if (lane >= o) ic += v;
  }
  if (lane == 63) wpart[wv] = ic;
  __syncthreads();
  int woff = 0;
  for (int i = 0; i < 4; ++i)
    if (i < wv) woff += wpart[i];
  int excl = woff + ic - lsum;
  offs[t * 4 + 0] = excl;
  offs[t * 4 + 1] = excl + c4.x;
  offs[t * 4 + 2] = excl + c4.x + c4.y;
  offs[t * 4 + 3] = excl + c4.x + c4.y + c4.z;
  __syncthreads();

  int k = argmin_i[b];
  int pos = atomicAdd(&cursor[k], 1);
  int o = offs[k] + pos;
  order[o] = b;
  korder[o] = k;
}

// -------- kernel 5: balanced chunk-scan gather (f16 Xh) ---------------------
__global__ __launch_bounds__(256) void gather_runs(
    const u16* __restrict__ Xh, const int* __restrict__ order,
    const int* __restrict__ korder, float* __restrict__ esum) {
  __shared__ int so[GROWS];
  __shared__ int sk[GROWS];
  int t = threadIdx.x;
  int base = blockIdx.x * GROWS;
  if (t < GROWS) {
    so[t] = order[base + t];
    sk[t] = korder[base + t];
  }
  __syncthreads();
  float a0 = 0.f, a1 = 0.f;
  int curk = sk[0];
#pragma unroll 8
  for (int m = 0; m < GROWS; ++m) {
    int k = sk[m];
    if (k != curk) {
      atomicAdd(&esum[(size_t)curk * ND + 2 * t], a0);
      atomicAdd(&esum[(size_t)curk * ND + 2 * t + 1], a1);
      a0 = 0.f; a1 = 0.f; curk = k;
    }
    u32 pr = *(const u32*)(Xh + (size_t)so[m] * ND + 2 * t);
    a0 += __half2float(__ushort_as_half((u16)(pr & 0xffffu)));
    a1 += __half2float(__ushort_as_half((u16)(pr >> 16)));
  }
  atomicAdd(&esum[(size_t)curk * ND + 2 * t], a0);
  atomicAdd(&esum[(size_t)curk * ND + 2 * t + 1], a1);
}

// --- kernel 6: fused: blocks [0,512) embed_avg EMA + weight (in-block
//     csnorm; db==0 writes out_ncs); blocks [512,912) hist EMA ---
__global__ __launch_bounds__(256) void ema_hist_kernel(
    const float* __restrict__ esum, const float* __restrict__ embed_avg,
    const int* __restrict__ counts, const float* __restrict__ cluster_size,
    const float* __restrict__ hist, const float* __restrict__ bhist,
    float* __restrict__ out_w, float* __restrict__ out_ea,
    float* __restrict__ out_ncs, float* __restrict__ out_hist) {
  __shared__ float tile[32][33];
  __shared__ float csn_s[32];
  __shared__ float wpart[4];
  int t = threadIdx.x;
  if (blockIdx.x >= 512) {
    int i = (blockIdx.x - 512) * 256 + t;
    out_hist[i] = hist[i] * 0.99f + 0.01f * bhist[i];
    return;
  }
  int kb = blockIdx.x & 31;
  int db = blockIdx.x >> 5;
  int tx = t & 31, ty = t >> 5;
  int lane = t & 63, wv = t >> 6;

  int4 c4 = ((const int4*)counts)[t];
  float4 cs4 = ((const float4*)cluster_size)[t];
  float n0 = cs4.x * 0.99f + 0.01f * (c4.x == 0 ? 1.0f : (float)c4.x);
  float n1 = cs4.y * 0.99f + 0.01f * (c4.y == 0 ? 1.0f : (float)c4.y);
  float n2 = cs4.z * 0.99f + 0.01f * (c4.z == 0 ? 1.0f : (float)c4.z);
  float n3 = cs4.w * 0.99f + 0.01f * (c4.w == 0 ? 1.0f : (float)c4.w);
  float ps = ((n0 + n1) + (n2 + n3));
#pragma unroll
  for (int m = 1; m < 64; m <<= 1) ps += __shfl_xor(ps, m, 64);
  if (lane == 0) wpart[wv] = ps;

#pragma unroll
  for (int i = 0; i < 4; ++i) {
    int kl = ty + i * 8;
    tile[kl][tx] = esum[(size_t)(kb * 32 + kl) * ND + db * 32 + tx];
  }
  __syncthreads();
  float n = wpart[0] + wpart[1] + wpart[2] + wpart[3];
  if (db == 0) {
    out_ncs[t * 4 + 0] = n0;
    out_ncs[t * 4 + 1] = n1;
    out_ncs[t * 4 + 2] = n2;
    out_ncs[t * 4 + 3] = n3;
  }
  if (t < 32) {
    int k = kb * 32 + t;
    int cnt = counts[k];
    float ncs = cluster_size[k] * 0.99f + 0.01f * (cnt == 0 ? 1.0f : (float)cnt);
    csn_s[t] = (ncs + 1e-5f) / (n + 1024.0f * 1e-5f) * n;
  }
  __syncthreads();
#pragma unroll
  for (int i = 0; i < 4; ++i) {
    int d = db * 32 + ty + i * 8;
    int k = kb * 32 + tx;
    size_t idx = (size_t)d * NK + k;
    float nea = embed_avg[idx] * 0.99f + 0.01f * tile[tx][ty + i * 8];
    out_ea[idx] = nea;
    out_w[idx] = nea / csn_s[tx];
  }
}

extern "C" void kernel_launch(void* const* d_in, const int* in_sizes, int n_in,
                              void* d_out, int out_size, void* d_ws, size_t ws_size,
                              hipStream_t stream) {
  const float* X = (const float*)d_in[0];
  const int* cls = (const int*)d_in[1];
  const float* W = (const float*)d_in[2];
  const float* cluster_size = (const float*)d_in[3];
  const float* embed_avg = (const float*)d_in[4];
  const float* hist = (const float*)d_in[5];

  float* wsf = (float*)d_ws;
  int* wsi = (int*)d_ws;
  int* counts = wsi + OFF_COUNTS;
  int* cursor = wsi + OFF_CURSOR;
  float* bhist = wsf + OFF_BHIST;
  int* flagCnt = wsi + OFF_FLAGCNT;
  float* wsq = wsf + OFF_WSQ;
  int* flagList = wsi + OFF_FLAGLIST;
  int* argmin_i = wsi + OFF_ARGMIN;
  int* order = wsi + OFF_ORDER;
  int* korder = wsi + OFF_KORDER;
  u16* Wthi = (u16*)(wsf + OFF_WTHI);
  float* Wt32 = wsf + OFF_WT32;
  u16* Xh = (u16*)(wsf + OFF_XH);
  float* esum = wsf + OFF_ESUM;

  float* out = (float*)d_out;
  float* out_w = out;
  float* out_ncs = out + (size_t)ND * NK;
  float* out_ea = out_ncs + NK;
  float* out_hist = out_ea + (size_t)ND * NK;
  float* out_arg = out_hist + (size_t)NK * NC;

  hipMemsetAsync(d_ws, 0, (size_t)OFF_ZERO_END * 4, stream);

  prep_all<<<512 + NB * ND / 8 / 256, 256, 0, stream>>>(W, X, Wthi, Wt32, Xh,
                                                        wsq);
  argmin_t64<<<NB / 64, 256, 0, stream>>>(Xh, Wthi, wsq, cls, argmin_i,
                                          out_arg, counts, bhist, flagCnt,
                                          flagList);
  fixup_kernel<<<FLAG_CAP / FROWS, 256, 0, stream>>>(X, Wt32, wsq, flagCnt,
                                                     flagList, cls, argmin_i,
                                                     out_arg, counts, bhist);
  reorder_kernel<<<NB / 256, 256, 0, stream>>>(argmin_i, counts, cursor, order,
                                               korder, esum);
  gather_runs<<<NB / GROWS, 256, 0, stream>>>(Xh, order, korder, esum);
  ema_hist_kernel<<<512 + (NK * NC) / 256, 256, 0, stream>>>(
      esum, embed_avg, counts, cluster_size, hist, bhist, out_w, out_ea,
      out_ncs, out_hist);
}

// Round 21
// 359.327 us; speedup vs baseline: 1.1033x; 1.1033x over previous
//
#include <hip/hip_runtime.h>
#include <hip/hip_fp16.h>

// clusteringEMA: B=65536, D=512, K=1024, C=100
// R21 = R19 verbatim (session best: 360.9us). argmin = r17's argmin_pair
// (141us, 0 conflicts, 2 blocks/CU — TLP ladder mapped: 1blk=260, 2blk=141,
// 3blk=183 => 2 is the optimum). 6-launch fused tail.

#define NB 65536
#define ND 512
#define NK 1024
#define NC 100
#define TAU 0.25f
#define FLAG_CAP 16384
#define FROWS 8
#define GROWS 128

typedef unsigned int u32;
typedef unsigned short u16;
typedef unsigned long long u64;
typedef __attribute__((ext_vector_type(8))) _Float16 half8v;
typedef __attribute__((ext_vector_type(4))) float f32x4;

// ---------------- ws layout (4-byte units) ----------------
#define OFF_COUNTS   0          // int [1024]
#define OFF_CURSOR   1024       // int [1024]
#define OFF_BHIST    2048       // float [102400]
#define OFF_FLAGCNT  104448     // int [64]
#define OFF_WSQ      104512     // float [1024]
#define OFF_ZERO_END 105536
#define OFF_FLAGLIST 105536     // int [16384]
#define OFF_ARGMIN   156736     // int [65536]
#define OFF_ORDER    222272     // int [65536]
#define OFF_KORDER   287808     // int [65536]
#define OFF_WTHI     353344     // u16 [524288] = 262144 float slots
#define OFF_WT32     615488     // float [524288]
#define OFF_XH       1139776    // u16 [33554432] = 16777216 float slots
#define OFF_ESUM     17916992   // float [524288]

__device__ inline f32x4 mfma16f(half8v a, half8v b, f32x4 c) {
  return __builtin_amdgcn_mfma_f32_16x16x32_f16(a, b, c, 0, 0, 0);
}

__device__ __forceinline__ void gl_lds16(const u16* g, u16* l) {
  __builtin_amdgcn_global_load_lds(
      (const __attribute__((address_space(1))) u32*)g,
      (__attribute__((address_space(3))) u32*)l, 16, 0, 0);
}

__device__ inline u32 f32_sortable(float f) {
  u32 b = __float_as_uint(f);
  return (b & 0x80000000u) ? ~b : (b | 0x80000000u);
}

__device__ inline half8v cvt8_f16(const float4& a, const float4& b) {
  half8v h;
  h[0] = (_Float16)a.x; h[1] = (_Float16)a.y;
  h[2] = (_Float16)a.z; h[3] = (_Float16)a.w;
  h[4] = (_Float16)b.x; h[5] = (_Float16)b.y;
  h[6] = (_Float16)b.z; h[7] = (_Float16)b.w;
  return h;
}

// ------ kernel 1: fused prep: blocks [0,512) = W transpose+split+wsq;
//                  blocks [512, 512+16384) = X -> Xh f16 ------
__global__ __launch_bounds__(256) void prep_all(const float* __restrict__ W,
                                                const float* __restrict__ X,
                                                u16* __restrict__ Wthi,
                                                float* __restrict__ Wt32,
                                                u16* __restrict__ Xh,
                                                float* __restrict__ wsq) {
  __shared__ float tile[32][33];
  int t = threadIdx.x;
  if (blockIdx.x >= 512) {
    size_t i = ((size_t)(blockIdx.x - 512) * 256 + t) * 8;
    float4 a = *(const float4*)(X + i);
    float4 b = *(const float4*)(X + i + 4);
    *(half8v*)(Xh + i) = cvt8_f16(a, b);
    return;
  }
  int db = blockIdx.x & 15;
  int kb = blockIdx.x >> 4;
  int tx = t & 31, ty = t >> 5;
  float s = 0.f;
#pragma unroll
  for (int i = 0; i < 4; ++i) {
    int d = db * 32 + ty + 8 * i;
    float wv = W[(size_t)d * NK + kb * 32 + tx];
    tile[ty + 8 * i][tx] = wv;
    s += wv * wv;
  }
  atomicAdd(&wsq[kb * 32 + tx], s);
  __syncthreads();
#pragma unroll
  for (int i = 0; i < 4; ++i) {
    int kl = ty + 8 * i;
    float f = tile[tx][kl];
    size_t o = (size_t)(kb * 32 + kl) * ND + db * 32 + tx;
    Wt32[o] = f;
    Wthi[o] = __half_as_ushort(__float2half(f));
  }
}

// --- kernel 2: argmin MFMA (r17): 256-col ct passes, k-paired B layout ------
__global__ __launch_bounds__(256, 2) void argmin_pair(
    const u16* __restrict__ Xh, const u16* __restrict__ Wthi,
    const float* __restrict__ wsq, const int* __restrict__ cls,
    int* __restrict__ argmin_i, float* __restrict__ argmin_f,
    int* __restrict__ counts, float* __restrict__ bhist,
    int* __restrict__ flagCnt, int* __restrict__ flagList) {
  __shared__ __align__(16) u16 Ah[2 * 128 * 64];
  __shared__ __align__(16) u16 Bh[2 * 128 * 64];
  __shared__ float wsq_s[NK];
  __shared__ float redV[128][2];
  __shared__ float redS[128][2];
  __shared__ int redI[128][2];

  const int t = threadIdx.x;
  const int lane = t & 63;
  const int w = t >> 6;
  const int g = lane >> 4;
  const int l15 = lane & 15;
  const int wrb = (w >> 1) * 64;
  const int wcb = (w & 1) * 128;
  const int brow = blockIdx.x * 128;

#pragma unroll
  for (int i = 0; i < 4; ++i) wsq_s[t + 256 * i] = wsq[t + 256 * i];

  const int sub = lane >> 3;
  const int c8p = lane & 7;
  const size_t asrc = (size_t)(brow + w * 32 + sub) * ND + (size_t)((c8p ^ sub) * 8);
  const size_t bsrc = (size_t)(2 * (w * 32 + sub) + (c8p >> 2)) * ND +
                      (size_t)(((c8p & 3) ^ (sub & 3)) * 8);

  int aofs[2];
#pragma unroll
  for (int kk = 0; kk < 2; ++kk)
    aofs[kk] = (wrb + l15) * 64 + (((kk * 4 + g) ^ (l15 & 7)) * 8);
  const int bofs = wcb * 32 + (l15 >> 1) * 64 + (l15 & 1) * 32 +
                   ((g ^ ((l15 >> 1) & 3)) * 8);

  float bestV[4][4], secV[4][4];
  int bestI[4][4];
#pragma unroll
  for (int m = 0; m < 4; ++m)
#pragma unroll
    for (int r = 0; r < 4; ++r) {
      bestV[m][r] = 3.4e38f; secV[m][r] = 3.4e38f; bestI[m][r] = 0;
    }

  f32x4 acc[4][8];
#pragma unroll
  for (int m = 0; m < 4; ++m)
#pragma unroll
    for (int n = 0; n < 8; ++n) acc[m][n] = (f32x4)0.f;

#define ISSUE_A(kc_, ab_)                                                \
  {                                                                      \
    const u16* as_ = Xh + asrc + (kc_) * 64;                             \
    u16* ad_ = Ah + (ab_) * 8192 + w * 32 * 64;                          \
    _Pragma("unroll")                                                    \
    for (int q = 0; q < 4; ++q)                                          \
      gl_lds16(as_ + (size_t)(q * 8) * ND, ad_ + q * 8 * 64);            \
  }
#define ISSUE_B(ct_, sk_, bb_)                                           \
  {                                                                      \
    const u16* bs_ = Wthi + (size_t)(ct_) * 256 * ND + bsrc + (sk_) * 32;\
    u16* bd_ = Bh + (bb_) * 8192 + w * 32 * 64;                          \
    _Pragma("unroll")                                                    \
    for (int q = 0; q < 4; ++q)                                          \
      gl_lds16(bs_ + (size_t)(q * 16) * ND, bd_ + q * 8 * 64);           \
  }
#define DRAIN asm volatile("s_waitcnt vmcnt(0) lgkmcnt(0)" ::: "memory")

  ISSUE_A(0, 0);
  ISSUE_B(0, 0, 0);
  DRAIN;
  __syncthreads();

  for (int s = 0; s < 64; ++s) {
    const int sk = s & 15;
    const int kpar = s & 1;
    const int abuf = (s >> 1) & 1;
    const int bbuf = s & 1;
    if (s < 63) {
      const int s1 = s + 1;
      ISSUE_B(s1 >> 4, s1 & 15, s1 & 1);
      if (s & 1) ISSUE_A(((s1 & 15) >> 1), (s1 >> 1) & 1);
    }
    const u16* Ab = Ah + abuf * 8192;
    const u16* Bb = Bh + bbuf * 8192;
    {
      half8v a_h[4];
#pragma unroll
      for (int m = 0; m < 4; ++m)
        a_h[m] = *(const half8v*)&Ab[aofs[kpar] + m * 1024];
#pragma unroll
      for (int n = 0; n < 8; ++n) {
        half8v b_h = *(const half8v*)&Bb[bofs + n * 512];
#pragma unroll
        for (int m = 0; m < 4; ++m)
          acc[m][n] = mfma16f(a_h[m], b_h, acc[m][n]);
      }
    }
    if (sk == 15) {
      const int ct = s >> 4;
#pragma unroll
      for (int n = 0; n < 8; ++n) {
        int col = ct * 256 + wcb + 16 * n + l15;
        float wq = wsq_s[col];
#pragma unroll
        for (int m = 0; m < 4; ++m)
#pragma unroll
          for (int r = 0; r < 4; ++r) {
            float v = wq - 2.0f * acc[m][n][r];
            if (v < bestV[m][r]) {
              secV[m][r] = bestV[m][r];
              bestV[m][r] = v;
              bestI[m][r] = col;
            } else if (v < secV[m][r]) {
              secV[m][r] = v;
            }
          }
      }
#pragma unroll
      for (int m = 0; m < 4; ++m)
#pragma unroll
        for (int n = 0; n < 8; ++n) acc[m][n] = (f32x4)0.f;
    }
    DRAIN;
    __syncthreads();
  }
#undef ISSUE_A
#undef ISSUE_B
#undef DRAIN

#pragma unroll
  for (int m = 0; m < 4; ++m)
#pragma unroll
    for (int r = 0; r < 4; ++r) {
      float v = bestV[m][r];
      float sec = secV[m][r];
      int idx = bestI[m][r];
#pragma unroll
      for (int mask = 1; mask < 16; mask <<= 1) {
        float ov = __shfl_xor(v, mask, 64);
        float os = __shfl_xor(sec, mask, 64);
        int oi = __shfl_xor(idx, mask, 64);
        float nsec = fminf(fminf(sec, os), fmaxf(v, ov));
        if (ov < v || (ov == v && oi < idx)) { v = ov; idx = oi; }
        sec = nsec;
      }
      if (l15 == 0) {
        int rowl = wrb + 16 * m + 4 * g + r;
        redV[rowl][w & 1] = v;
        redS[rowl][w & 1] = sec;
        redI[rowl][w & 1] = idx;
      }
    }
  __syncthreads();
  if (t < 128) {
    float v0 = redV[t][0], v1 = redV[t][1];
    float s0 = redS[t][0], s1 = redS[t][1];
    int i0 = redI[t][0], i1 = redI[t][1];
    float bv, sec;
    int bi;
    if (v1 < v0 || (v1 == v0 && i1 < i0)) { bv = v1; bi = i1; }
    else { bv = v0; bi = i0; }
    sec = fminf(fminf(s0, s1), fmaxf(v0, v1));
    int b = brow + t;
    argmin_i[b] = bi;
    argmin_f[b] = (float)bi;
    atomicAdd(&counts[bi], 1);
    atomicAdd(&bhist[(size_t)bi * NC + cls[b]], 1.0f);
    if (sec - bv < TAU) {
      int slot = atomicAdd(flagCnt, 1);
      if (slot < FLAG_CAP) flagList[slot] = b;
    }
  }
}

// ----- kernel 3: exact f32 rescore + in-place apply (block owns its rows) ---
__global__ __launch_bounds__(256) void fixup_kernel(
    const float* __restrict__ X, const float* __restrict__ Wt32,
    const float* __restrict__ wsq, const int* __restrict__ flagCnt,
    const int* __restrict__ flagList, const int* __restrict__ cls,
    int* __restrict__ argmin_i, float* __restrict__ argmin_f,
    int* __restrict__ counts, float* __restrict__ bhist) {
  __shared__ float xs[FROWS][ND];
  __shared__ int rows[FROWS];
  __shared__ u64 wred[4][FROWS];
  int n = *flagCnt;
  if (n > FLAG_CAP) n = FLAG_CAP;
  int r0 = blockIdx.x * FROWS;
  if (r0 >= n) return;
  int nr = n - r0; if (nr > FROWS) nr = FROWS;
  int t = threadIdx.x;
  if (t < FROWS) rows[t] = flagList[r0 + (t < nr ? t : 0)];
  __syncthreads();
  for (int j = t; j < FROWS * (ND / 4); j += 256) {
    int r = j >> 7, c = j & 127;
    ((float4*)xs[r])[c] = ((const float4*)(X + (size_t)rows[r] * ND))[c];
  }
  __syncthreads();

  const int k0 = t * 4;
  const float4* w0 = (const float4*)(Wt32 + (size_t)(k0 + 0) * ND);
  const float4* w1 = (const float4*)(Wt32 + (size_t)(k0 + 1) * ND);
  const float4* w2 = (const float4*)(Wt32 + (size_t)(k0 + 2) * ND);
  const float4* w3 = (const float4*)(Wt32 + (size_t)(k0 + 3) * ND);
  float a[4][FROWS];
#pragma unroll
  for (int kk = 0; kk < 4; ++kk)
#pragma unroll
    for (int r = 0; r < FROWS; ++r) a[kk][r] = 0.f;

  for (int d = 0; d < ND / 4; ++d) {
    float4 v0 = w0[d], v1 = w1[d], v2 = w2[d], v3 = w3[d];
#pragma unroll
    for (int r = 0; r < FROWS; ++r) {
      float4 x4 = ((const float4*)xs[r])[d];
      a[0][r] += x4.x * v0.x + x4.y * v0.y + x4.z * v0.z + x4.w * v0.w;
      a[1][r] += x4.x * v1.x + x4.y * v1.y + x4.z * v1.z + x4.w * v1.w;
      a[2][r] += x4.x * v2.x + x4.y * v2.y + x4.z * v2.z + x4.w * v2.w;
      a[3][r] += x4.x * v3.x + x4.y * v3.y + x4.z * v3.z + x4.w * v3.w;
    }
  }

  float wq0 = wsq[k0], wq1 = wsq[k0 + 1], wq2 = wsq[k0 + 2], wq3 = wsq[k0 + 3];
  const int wv_ = t >> 6, lane = t & 63;
#pragma unroll
  for (int r = 0; r < FROWS; ++r) {
    float bv = wq0 - 2.0f * a[0][r];
    int bk = k0;
    float v;
    v = wq1 - 2.0f * a[1][r]; if (v < bv) { bv = v; bk = k0 + 1; }
    v = wq2 - 2.0f * a[2][r]; if (v < bv) { bv = v; bk = k0 + 2; }
    v = wq3 - 2.0f * a[3][r]; if (v < bv) { bv = v; bk = k0 + 3; }
    u64 key = ((u64)f32_sortable(bv) << 32) | (u32)bk;
#pragma unroll
    for (int m = 1; m < 64; m <<= 1) {
      u64 o = __shfl_xor(key, m, 64);
      if (o < key) key = o;
    }
    if (lane == 0) wred[wv_][r] = key;
  }
  __syncthreads();
  if (t < nr) {
    u64 k = wred[0][t];
    if (wred[1][t] < k) k = wred[1][t];
    if (wred[2][t] < k) k = wred[2][t];
    if (wred[3][t] < k) k = wred[3][t];
    int nk = (int)(u32)(k & 0xffffffffu);
    int row = rows[t];
    int old = argmin_i[row];
    if (nk != old) {
      argmin_i[row] = nk;
      argmin_f[row] = (float)nk;
      atomicSub(&counts[old], 1);
      atomicAdd(&counts[nk], 1);
      int c = cls[row];
      atomicAdd(&bhist[(size_t)old * NC + c], -1.0f);
      atomicAdd(&bhist[(size_t)nk * NC + c], 1.0f);
    }
  }
}

// --------- kernel 4: reorder rows + in-block offsets scan + zero esum -------
__global__ __launch_bounds__(256) void reorder_kernel(
    const int* __restrict__ argmin_i, const int* __restrict__ counts,
    int* __restrict__ cursor, int* __restrict__ order,
    int* __restrict__ korder, float* __restrict__ esum) {
  __shared__ int offs[NK];
  __shared__ int wpart[4];
  int t = threadIdx.x, lane = t & 63, wv = t >> 6;
  int b = blockIdx.x * 256 + t;

  float4 z = make_float4(0.f, 0.f, 0.f, 0.f);
  *(float4*)(esum + (size_t)b * 8) = z;
  *(float4*)(esum + (size_t)b * 8 + 4) = z;

  int4 c4 = ((const int4*)counts)[t];
  int lsum = c4.x + c4.y + c4.z + c4.w;
  int ic = lsum;
#pragma unroll
  for (int o = 1; o < 64; o <<= 1) {
    int v = __shfl_up(ic, o, 64);
    if (lane >= o) ic += v;
  }
  if (lane == 63) wpart[wv] = ic;
  __syncthreads();
  int woff = 0;
  for (int i = 0; i < 4; ++i)
    if (i < wv) woff += wpart[i];
  int excl = woff + ic - lsum;
  offs[t * 4 + 0] = excl;
  offs[t * 4 + 1] = excl + c4.x;
  offs[t * 4 + 2] = excl + c4.x + c4.y;
  offs[t * 4 + 3] = excl + c4.x + c4.y + c4.z;
  __syncthreads();

  int k = argmin_i[b];
  int pos = atomicAdd(&cursor[k], 1);
  int o = offs[k] + pos;
  order[o] = b;
  korder[o] = k;
}

// -------- kernel 5: balanced chunk-scan gather (f16 Xh) ---------------------
__global__ __launch_bounds__(256) void gather_runs(
    const u16* __restrict__ Xh, const int* __restrict__ order,
    const int* __restrict__ korder, float* __restrict__ esum) {
  __shared__ int so[GROWS];
  __shared__ int sk[GROWS];
  int t = threadIdx.x;
  int base = blockIdx.x * GROWS;
  if (t < GROWS) {
    so[t] = order[base + t];
    sk[t] = korder[base + t];
  }
  __syncthreads();
  float a0 = 0.f, a1 = 0.f;
  int curk = sk[0];
#pragma unroll 8
  for (int m = 0; m < GROWS; ++m) {
    int k = sk[m];
    if (k != curk) {
      atomicAdd(&esum[(size_t)curk * ND + 2 * t], a0);
      atomicAdd(&esum[(size_t)curk * ND + 2 * t + 1], a1);
      a0 = 0.f; a1 = 0.f; curk = k;
    }
    u32 pr = *(const u32*)(Xh + (size_t)so[m] * ND + 2 * t);
    a0 += __half2float(__ushort_as_half((u16)(pr & 0xffffu)));
    a1 += __half2float(__ushort_as_half((u16)(pr >> 16)));
  }
  atomicAdd(&esum[(size_t)curk * ND + 2 * t], a0);
  atomicAdd(&esum[(size_t)curk * ND + 2 * t + 1], a1);
}

// --- kernel 6: fused: blocks [0,512) embed_avg EMA + weight (in-block
//     csnorm; db==0 writes out_ncs); blocks [512,912) hist EMA ---
__global__ __launch_bounds__(256) void ema_hist_kernel(
    const float* __restrict__ esum, const float* __restrict__ embed_avg,
    const int* __restrict__ counts, const float* __restrict__ cluster_size,
    const float* __restrict__ hist, const float* __restrict__ bhist,
    float* __restrict__ out_w, float* __restrict__ out_ea,
    float* __restrict__ out_ncs, float* __restrict__ out_hist) {
  __shared__ float tile[32][33];
  __shared__ float csn_s[32];
  __shared__ float wpart[4];
  int t = threadIdx.x;
  if (blockIdx.x >= 512) {
    int i = (blockIdx.x - 512) * 256 + t;
    out_hist[i] = hist[i] * 0.99f + 0.01f * bhist[i];
    return;
  }
  int kb = blockIdx.x & 31;
  int db = blockIdx.x >> 5;
  int tx = t & 31, ty = t >> 5;
  int lane = t & 63, wv = t >> 6;

  int4 c4 = ((const int4*)counts)[t];
  float4 cs4 = ((const float4*)cluster_size)[t];
  float n0 = cs4.x * 0.99f + 0.01f * (c4.x == 0 ? 1.0f : (float)c4.x);
  float n1 = cs4.y * 0.99f + 0.01f * (c4.y == 0 ? 1.0f : (float)c4.y);
  float n2 = cs4.z * 0.99f + 0.01f * (c4.z == 0 ? 1.0f : (float)c4.z);
  float n3 = cs4.w * 0.99f + 0.01f * (c4.w == 0 ? 1.0f : (float)c4.w);
  float ps = ((n0 + n1) + (n2 + n3));
#pragma unroll
  for (int m = 1; m < 64; m <<= 1) ps += __shfl_xor(ps, m, 64);
  if (lane == 0) wpart[wv] = ps;

#pragma unroll
  for (int i = 0; i < 4; ++i) {
    int kl = ty + i * 8;
    tile[kl][tx] = esum[(size_t)(kb * 32 + kl) * ND + db * 32 + tx];
  }
  __syncthreads();
  float n = wpart[0] + wpart[1] + wpart[2] + wpart[3];
  if (db == 0) {
    out_ncs[t * 4 + 0] = n0;
    out_ncs[t * 4 + 1] = n1;
    out_ncs[t * 4 + 2] = n2;
    out_ncs[t * 4 + 3] = n3;
  }
  if (t < 32) {
    int k = kb * 32 + t;
    int cnt = counts[k];
    float ncs = cluster_size[k] * 0.99f + 0.01f * (cnt == 0 ? 1.0f : (float)cnt);
    csn_s[t] = (ncs + 1e-5f) / (n + 1024.0f * 1e-5f) * n;
  }
  __syncthreads();
#pragma unroll
  for (int i = 0; i < 4; ++i) {
    int d = db * 32 + ty + i * 8;
    int k = kb * 32 + tx;
    size_t idx = (size_t)d * NK + k;
    float nea = embed_avg[idx] * 0.99f + 0.01f * tile[tx][ty + i * 8];
    out_ea[idx] = nea;
    out_w[idx] = nea / csn_s[tx];
  }
}

extern "C" void kernel_launch(void* const* d_in, const int* in_sizes, int n_in,
                              void* d_out, int out_size, void* d_ws, size_t ws_size,
                              hipStream_t stream) {
  const float* X = (const float*)d_in[0];
  const int* cls = (const int*)d_in[1];
  const float* W = (const float*)d_in[2];
  const float* cluster_size = (const float*)d_in[3];
  const float* embed_avg = (const float*)d_in[4];
  const float* hist = (const float*)d_in[5];

  float* wsf = (float*)d_ws;
  int* wsi = (int*)d_ws;
  int* counts = wsi + OFF_COUNTS;
  int* cursor = wsi + OFF_CURSOR;
  float* bhist = wsf + OFF_BHIST;
  int* flagCnt = wsi + OFF_FLAGCNT;
  float* wsq = wsf + OFF_WSQ;
  int* flagList = wsi + OFF_FLAGLIST;
  int* argmin_i = wsi + OFF_ARGMIN;
  int* order = wsi + OFF_ORDER;
  int* korder = wsi + OFF_KORDER;
  u16* Wthi = (u16*)(wsf + OFF_WTHI);
  float* Wt32 = wsf + OFF_WT32;
  u16* Xh = (u16*)(wsf + OFF_XH);
  float* esum = wsf + OFF_ESUM;

  float* out = (float*)d_out;
  float* out_w = out;
  float* out_ncs = out + (size_t)ND * NK;
  float* out_ea = out_ncs + NK;
  float* out_hist = out_ea + (size_t)ND * NK;
  float* out_arg = out_hist + (size_t)NK * NC;

  hipMemsetAsync(d_ws, 0, (size_t)OFF_ZERO_END * 4, stream);

  prep_all<<<512 + NB * ND / 8 / 256, 256, 0, stream>>>(W, X, Wthi, Wt32, Xh,
                                                        wsq);
  argmin_pair<<<NB / 128, 256, 0, stream>>>(Xh, Wthi, wsq, cls, argmin_i,
                                            out_arg, counts, bhist, flagCnt,
                                            flagList);
  fixup_kernel<<<FLAG_CAP / FROWS, 256, 0, stream>>>(X, Wt32, wsq, flagCnt,
                                                     flagList, cls, argmin_i,
                                                     out_arg, counts, bhist);
  reorder_kernel<<<NB / 256, 256, 0, stream>>>(argmin_i, counts, cursor, order,
                                               korder, esum);
  gather_runs<<<NB / GROWS, 256, 0, stream>>>(Xh, order, korder, esum);
  ema_hist_kernel<<<512 + (NK * NC) / 256, 256, 0, stream>>>(
      esum, embed_avg, counts, cluster_size, hist, bhist, out_w, out_ea,
      out_ncs, out_hist);
}